// Round 1
// baseline (267.717 us; speedup 1.0000x reference)
//
#include <hip/hip_runtime.h>
#include <math.h>

// Problem constants (match reference)
#define ALPHA     1.0f
#define BETA      0.001f
#define GAMMA     0.1f
#define THRESH    0.5f
#define LOG_CLAMP -100.0f

constexpr int B = 256, C = 2, H = 192, W = 256;
constexpr int HW   = H * W;          // 49152
constexpr int HW4  = HW / 4;         // 12288 float4 per (b,c) slab
constexpr long long NTOT = (long long)B * C * H * W;  // 25165824
constexpr int N4   = (int)(NTOT / 4);                  // 6291456

__device__ __forceinline__ float wave_reduce(float v) {
#pragma unroll
    for (int off = 32; off > 0; off >>= 1)
        v += __shfl_down(v, off, 64);
    return v;
}

__global__ void zero_ws(float* ws) {
    ws[0] = 0.0f;  // bce sum
    ws[1] = 0.0f;  // cuts count
    ws[2] = 0.0f;  // dense sum
}

// ---- BCE sum over all elements + channel-0 count(>0.5), float4 vectorized ----
__global__ __launch_bounds__(256) void bce_cuts_kernel(
        const float4* __restrict__ p4,
        const float4* __restrict__ t4,
        float* __restrict__ ws) {
    float bce  = 0.0f;
    float cuts = 0.0f;
    const int stride = gridDim.x * blockDim.x;
    for (int f = blockIdx.x * blockDim.x + threadIdx.x; f < N4; f += stride) {
        float4 p = p4[f];
        float4 t = t4[f];
        int c = (f / HW4) & 1;   // channel of this float4 (HW divisible by 4)

        bce += t.x * fmaxf(logf(p.x), LOG_CLAMP) + (1.0f - t.x) * fmaxf(log1pf(-p.x), LOG_CLAMP);
        bce += t.y * fmaxf(logf(p.y), LOG_CLAMP) + (1.0f - t.y) * fmaxf(log1pf(-p.y), LOG_CLAMP);
        bce += t.z * fmaxf(logf(p.z), LOG_CLAMP) + (1.0f - t.z) * fmaxf(log1pf(-p.z), LOG_CLAMP);
        bce += t.w * fmaxf(logf(p.w), LOG_CLAMP) + (1.0f - t.w) * fmaxf(log1pf(-p.w), LOG_CLAMP);

        if (c == 0) {
            cuts += (p.x > THRESH ? 1.0f : 0.0f)
                  + (p.y > THRESH ? 1.0f : 0.0f)
                  + (p.z > THRESH ? 1.0f : 0.0f)
                  + (p.w > THRESH ? 1.0f : 0.0f);
        }
    }

    __shared__ float sb[4], sc[4];
    float rb = wave_reduce(bce);
    float rc = wave_reduce(cuts);
    const int lane = threadIdx.x & 63;
    const int wid  = threadIdx.x >> 6;
    if (lane == 0) { sb[wid] = rb; sc[wid] = rc; }
    __syncthreads();
    if (threadIdx.x == 0) {
        atomicAdd(&ws[0], sb[0] + sb[1] + sb[2] + sb[3]);
        atomicAdd(&ws[1], sc[0] + sc[1] + sc[2] + sc[3]);
    }
}

// ---- dense penalty: one thread per (b, w) column of channel 1 ----
// Replicates lax.scan over i = 0 .. H-2:
//   m = p > 0.5 ; if (m && prev != 0) acc += 1/(i-prev)^3 ; if (m) prev = i
__global__ __launch_bounds__(256) void dense_kernel(
        const float* __restrict__ in,
        float* __restrict__ ws) {
    const int j = blockIdx.x * blockDim.x + threadIdx.x;  // 0 .. B*W-1
    const int b = j >> 8;       // W == 256
    const int w = j & 255;
    const float* col = in + ((b * 2 + 1) * H) * W + w;  // channel 1 of batch b

    int prev = 0;
    float acc = 0.0f;
#pragma unroll 8
    for (int i = 0; i < H - 1; ++i) {
        const bool m = col[i * W] > THRESH;
        const float d = (float)(i - prev);
        const float add = 1.0f / (d * d * d);
        acc += (m && prev != 0) ? add : 0.0f;
        prev = m ? i : prev;
    }

    __shared__ float sd[4];
    float r = wave_reduce(acc);
    const int lane = threadIdx.x & 63;
    const int wid  = threadIdx.x >> 6;
    if (lane == 0) sd[wid] = r;
    __syncthreads();
    if (threadIdx.x == 0)
        atomicAdd(&ws[2], sd[0] + sd[1] + sd[2] + sd[3]);
}

__global__ void finalize_kernel(const float* __restrict__ ws,
                                float* __restrict__ out) {
    const float bce = -ws[0] / (float)NTOT;
    out[0] = ALPHA * bce + BETA * ws[1] + GAMMA * ws[2];
}

extern "C" void kernel_launch(void* const* d_in, const int* in_sizes, int n_in,
                              void* d_out, int out_size, void* d_ws, size_t ws_size,
                              hipStream_t stream) {
    const float* inputs  = (const float*)d_in[0];
    const float* targets = (const float*)d_in[1];
    float* out = (float*)d_out;
    float* ws  = (float*)d_ws;

    zero_ws<<<1, 1, 0, stream>>>(ws);

    // 3072 blocks * 256 threads * 8 float4/thread == 6291456 == N4 exactly
    bce_cuts_kernel<<<3072, 256, 0, stream>>>(
        (const float4*)inputs, (const float4*)targets, ws);

    // B*W = 65536 columns, one thread each
    dense_kernel<<<256, 256, 0, stream>>>(inputs, ws);

    finalize_kernel<<<1, 1, 0, stream>>>(ws, out);
}